// Round 1
// 362.488 us; speedup vs baseline: 1.0557x; 1.0557x over previous
//
#include <hip/hip_runtime.h>
#include <hip/hip_fp16.h>

typedef __attribute__((ext_vector_type(8))) _Float16 half8;  // MFMA A/B frag (4 VGPRs)
typedef __attribute__((ext_vector_type(4))) float floatx4;   // MFMA C/D frag
typedef __attribute__((ext_vector_type(8))) ushort ushortx8; // 16B of fp16 bits

#define TILE 128
#define BK 64
// LDS tiles unpadded: 128 rows x 64 elems (128B rows). global_load_lds needs
// wave-uniform base + lane*16 dests. Bank conflicts broken by XOR chunk swizzle:
// LDS chunk c of row r holds global chunk c ^ (r & 7). Frag reads: 16 lanes
// spread over 8 chunks -> 2-way, free (m136). DMA applies XOR on global side.

__device__ inline ushort f2h(float f) {
    _Float16 h = (_Float16)f;
    ushort u; __builtin_memcpy(&u, &h, 2); return u;
}
__device__ inline float h2f(ushort u) {
    _Float16 h; __builtin_memcpy(&h, &u, 2);
    return (float)h;
}

// async 16B/lane global->LDS DMA; lds dest = base + lane*16 (implicit)
__device__ inline void async_copy16(const ushort* g, ushort* lds) {
    __builtin_amdgcn_global_load_lds(
        (const __attribute__((address_space(1))) void*)(const void*)g,
        (__attribute__((address_space(3))) void*)(void*)lds,
        16, 0, 0);
}

// XCD-aware remap (8 XCDs, flat id dispatched x-fastest, XCD = flat % 8
// round-robin heuristic). Groups all X blocks of a y-row onto ONE XCD with
// consecutive issue order, so row-shared A tiles are fetched into L2 once.
// Pure permutation: correctness-neutral if the placement assumption is wrong.
__device__ inline void xcd_swizzle(int X, int YZ, int& bx, int& yz) {
    if ((YZ & 7) != 0) return;           // need YZ % 8 == 0
    const int flat = yz * X + bx;
    const int xcd  = flat & 7;
    const int t    = flat >> 3;          // rank within this XCD
    const int rows = YZ >> 3;            // y-rows per XCD
    yz = xcd * rows + t / X;
    bx = t % X;
}

// Core 128x128 NT tile loop, BK=64, fp16 MFMA. A/B pre-offset to tile origin.
// Both operands staged via async global_load_lds DMA (fp16 in HBM).
__device__ __forceinline__ void gemm_core(const ushort* __restrict__ A, int lda,
                                          const ushort* __restrict__ B, int ldb,
                                          int K, ushort* As, ushort* Bs,
                                          floatx4 acc[4][4])
{
    const int t    = threadIdx.x;
    const int lane = t & 63;
    const int wave = t >> 6;
    const int wr   = (wave >> 1) * 64;
    const int wc   = (wave & 1) * 64;
    const int lrow = lane & 15;
    const int srow = lane >> 3;                 // 0..7 within an 8-row DMA block
    const int gcol = ((lane & 7) ^ srow) * 8;   // global chunk, XOR-swizzled
    const int c0   = lane >> 4;                 // frag base chunk (k-quad)
    const int sw   = lane & 7;                  // frag row swizzle key

    for (int k0 = 0; k0 < K; k0 += BK) {
#pragma unroll
        for (int h = 0; h < 4; h++) {
            const int r0 = wave * 32 + h * 8;   // 8 rows per 1KB DMA
            async_copy16(A + (size_t)(r0 + srow) * lda + k0 + gcol, &As[r0 * 64]);
            async_copy16(B + (size_t)(r0 + srow) * ldb + k0 + gcol, &Bs[r0 * 64]);
        }
        __syncthreads();

#pragma unroll
        for (int step = 0; step < 2; step++) {
            half8 aF[4], bF[4];
            const int ch = ((4 * step + c0) ^ sw) * 8;
#pragma unroll
            for (int i = 0; i < 4; i++) {
                aF[i] = *(const half8*)(&As[(wr + i * 16 + lrow) * 64 + ch]);
                bF[i] = *(const half8*)(&Bs[(wc + i * 16 + lrow) * 64 + ch]);
            }
#pragma unroll
            for (int i = 0; i < 4; i++)
#pragma unroll
                for (int j = 0; j < 4; j++)
                    acc[i][j] = __builtin_amdgcn_mfma_f32_16x16x32_f16(aF[i], bF[j], acc[i][j], 0, 0, 0);
        }
        __syncthreads();
    }
}

// Epilogue. Cb pre-offset to tile origin; bias pre-offset to tileN.
// C/D layout: col=lane&15, row=(lane>>4)*4+reg.
template<int OM, bool TRANS, bool HB>
__device__ __forceinline__ void epilogue(floatx4 acc[4][4], void* Cb, int ldc,
                                         const float* bias, float scale)
{
    const int lane = threadIdx.x & 63;
    const int wave = threadIdx.x >> 6;
    const int wr = (wave >> 1) * 64, wc = (wave & 1) * 64;
    const int lrow = lane & 15, rq = (lane >> 4) * 4;
#pragma unroll
    for (int i = 0; i < 4; i++) {
#pragma unroll
        for (int j = 0; j < 4; j++) {
            const int n = wc + j * 16 + lrow;
            const float bv = HB ? bias[n] : 0.f;
#pragma unroll
            for (int r = 0; r < 4; r++) {
                const int m = wr + i * 16 + rq + r;
                const float val = acc[i][j][r] * scale + bv;
                const size_t idx = TRANS ? ((size_t)n * ldc + m) : ((size_t)m * ldc + n);
                if (OM == 0) ((float*)Cb)[idx] = val;
                else         ((ushort*)Cb)[idx] = f2h(val);
            }
        }
    }
}

// Generic fp16 NT GEMM (both operands DMA-staged), XCD-swizzled.
template<int OM, bool TRANS, bool HB>
__global__ __launch_bounds__(256)
void gemm_nt(const ushort* __restrict__ A, long long batchA, int lda,
             const ushort* __restrict__ B, long long batchB, int ldb,
             void* __restrict__ C, long long batchC, int ldc,
             const float* __restrict__ bias, float scale, int K)
{
    __shared__ ushort As[TILE * BK];
    __shared__ ushort Bs[TILE * BK];

    int bx = blockIdx.x;
    int yz = blockIdx.y + gridDim.y * blockIdx.z;
    xcd_swizzle(gridDim.x, gridDim.y * gridDim.z, bx, yz);
    const int by = yz % gridDim.y;
    const int bz = yz / gridDim.y;
    const int tileM = by * TILE, tileN = bx * TILE;

    floatx4 acc[4][4];
#pragma unroll
    for (int i = 0; i < 4; i++)
#pragma unroll
        for (int j = 0; j < 4; j++) acc[i][j] = (floatx4){0.f, 0.f, 0.f, 0.f};

    gemm_core(A + (size_t)bz * batchA + (size_t)tileM * lda, lda,
              B + (size_t)bz * batchB + (size_t)tileN * ldb, ldb,
              K, As, Bs, acc);

    const size_t coff = TRANS ? ((size_t)tileN * ldc + tileM) : ((size_t)tileM * ldc + tileN);
    void* Cb = (OM == 0) ? (void*)((float*)C + (size_t)bz * batchC + coff)
                         : (void*)((ushort*)C + (size_t)bz * batchC + coff);
    epilogue<OM, TRANS, HB>(acc, Cb, ldc, HB ? bias + tileN : nullptr, scale);
}

// Fused Q/K/V projections, one dispatch. logical grid (8, 192), XCD-swizzled:
//  y in [0,64): qp = q @ Wq^T + bq        (q pre-converted fp16)
//  y in [64,128): kp = k @ Wk^T + bk
//  y in [128,192): vpt_b = (v_b @ Wv^T + bv)^T   (b = (y-128)/16)
__global__ __launch_bounds__(256)
void qkv_proj(const ushort* __restrict__ q, const ushort* __restrict__ k,
              const ushort* __restrict__ v,
              const ushort* __restrict__ Wq, const ushort* __restrict__ Wk,
              const ushort* __restrict__ Wv,
              const float* __restrict__ bq, const float* __restrict__ bk,
              const float* __restrict__ bv,
              ushort* __restrict__ qp, ushort* __restrict__ kp,
              ushort* __restrict__ vpt)
{
    __shared__ ushort As[TILE * BK];
    __shared__ ushort Bs[TILE * BK];
    const int D = 1024, S = 2048;

    int bx = blockIdx.x, y = blockIdx.y;
    xcd_swizzle(8, 192, bx, y);
    const int tileN = bx * TILE;

    floatx4 acc[4][4];
#pragma unroll
    for (int i = 0; i < 4; i++)
#pragma unroll
        for (int j = 0; j < 4; j++) acc[i][j] = (floatx4){0.f, 0.f, 0.f, 0.f};

    if (y < 128) {           // block-uniform branch
        const bool isQ = (y < 64);
        const int my = isQ ? y : y - 64;
        const ushort* A = (isQ ? q : k) + (size_t)my * TILE * D;
        const ushort* W = (isQ ? Wq : Wk) + (size_t)tileN * D;
        gemm_core(A, D, W, D, D, As, Bs, acc);
        ushort* Cb = (isQ ? qp : kp) + (size_t)my * TILE * D + tileN;
        epilogue<1, false, true>(acc, Cb, D, (isQ ? bq : bk) + tileN, 1.0f);
    } else {
        const int yy = y - 128;
        const int bz = yy >> 4, my = yy & 15;
        const ushort* A = v + ((size_t)bz * S + (size_t)my * TILE) * D;
        gemm_core(A, D, Wv + (size_t)tileN * D, D, D, As, Bs, acc);
        ushort* Cb = vpt + (size_t)bz * D * S + (size_t)tileN * S + (size_t)my * TILE;
        epilogue<1, true, true>(acc, Cb, S, bv + tileN, 1.0f);
    }
}

// fp32 -> fp16 for the 4 weight matrices (D*D each); grid (512, 4)
__global__ __launch_bounds__(256)
void cvt_w(const float* __restrict__ w0, const float* __restrict__ w1,
           const float* __restrict__ w2, const float* __restrict__ w3,
           ushort* __restrict__ o0, ushort* __restrict__ o1,
           ushort* __restrict__ o2, ushort* __restrict__ o3)
{
    const float* src; ushort* dst;
    switch (blockIdx.y) {
        case 0: src = w0; dst = o0; break;
        case 1: src = w1; dst = o1; break;
        case 2: src = w2; dst = o2; break;
        default: src = w3; dst = o3; break;
    }
    const size_t i = ((size_t)blockIdx.x * 256 + threadIdx.x) * 8;
    floatx4 f0 = *(const floatx4*)(src + i);
    floatx4 f1 = *(const floatx4*)(src + i + 4);
    ushortx8 u;
    u[0] = f2h(f0.x); u[1] = f2h(f0.y); u[2] = f2h(f0.z); u[3] = f2h(f0.w);
    u[4] = f2h(f1.x); u[5] = f2h(f1.y); u[6] = f2h(f1.z); u[7] = f2h(f1.w);
    *(ushortx8*)(dst + i) = u;
}

// fp32 -> fp16 for q,k,v activations (B*S*D each); grid (4096, 3).
// BW-bound pre-pass so qkv_proj can use the async-DMA staging path.
__global__ __launch_bounds__(256)
void cvt_qkv(const float* __restrict__ q, const float* __restrict__ k,
             const float* __restrict__ v,
             ushort* __restrict__ qh, ushort* __restrict__ kh,
             ushort* __restrict__ vh)
{
    const float* src; ushort* dst;
    switch (blockIdx.y) {
        case 0: src = q; dst = qh; break;
        case 1: src = k; dst = kh; break;
        default: src = v; dst = vh; break;
    }
    const size_t i = ((size_t)blockIdx.x * 256 + threadIdx.x) * 8;
    floatx4 f0 = *(const floatx4*)(src + i);
    floatx4 f1 = *(const floatx4*)(src + i + 4);
    ushortx8 u;
    u[0] = f2h(f0.x); u[1] = f2h(f0.y); u[2] = f2h(f0.z); u[3] = f2h(f0.w);
    u[4] = f2h(f1.x); u[5] = f2h(f1.y); u[6] = f2h(f1.z); u[7] = f2h(f1.w);
    *(ushortx8*)(dst + i) = u;
}

// Row softmax over S=2048 pre-scaled fp16 logits; fp32 math; fp16 probs in place.
__global__ __launch_bounds__(256)
void softmax_rows(ushort* __restrict__ scores)
{
    const int S = 2048;
    ushort* srow = scores + (size_t)blockIdx.x * S;
    const int t    = threadIdx.x;
    const int lane = t & 63;
    const int w    = t >> 6;

    ushortx8 raw = *(const ushortx8*)(srow + t * 8);
    float l[8];
#pragma unroll
    for (int i = 0; i < 8; i++) l[i] = h2f(raw[i]);

    float m = l[0];
#pragma unroll
    for (int i = 1; i < 8; i++) m = fmaxf(m, l[i]);
#pragma unroll
    for (int off = 32; off >= 1; off >>= 1) m = fmaxf(m, __shfl_down(m, off));

    __shared__ float redm[4], reds[4];
    if (lane == 0) redm[w] = m;
    __syncthreads();
    m = fmaxf(fmaxf(redm[0], redm[1]), fmaxf(redm[2], redm[3]));

    float e[8], s = 0.f;
#pragma unroll
    for (int i = 0; i < 8; i++) { e[i] = __expf(l[i] - m); s += e[i]; }
#pragma unroll
    for (int off = 32; off >= 1; off >>= 1) s += __shfl_down(s, off);
    if (lane == 0) reds[w] = s;
    __syncthreads();
    s = reds[0] + reds[1] + reds[2] + reds[3];
    const float inv = 1.f / s;

    ushortx8 o;
#pragma unroll
    for (int i = 0; i < 8; i++) o[i] = f2h(e[i] * inv);
    *(ushortx8*)(srow + t * 8) = o;
}

extern "C" void kernel_launch(void* const* d_in, const int* in_sizes, int n_in,
                              void* d_out, int out_size, void* d_ws, size_t ws_size,
                              hipStream_t stream)
{
    const int B = 4, S = 2048, D = 1024;
    const size_t SD = (size_t)B * S * D;   // 8M elems
    const float* q  = (const float*)d_in[0];
    const float* k  = (const float*)d_in[1];
    const float* v  = (const float*)d_in[2];
    const float* Wq = (const float*)d_in[3];
    const float* bq = (const float*)d_in[4];
    const float* Wk = (const float*)d_in[5];
    const float* bk = (const float*)d_in[6];
    const float* Wv = (const float*)d_in[7];
    const float* bv = (const float*)d_in[8];
    const float* Wo = (const float*)d_in[9];
    const float* bo = (const float*)d_in[10];
    float* out = (float*)d_out;

    // ws (ushort): qp 16MB | kp 16MB | sc 33.5MB | W16 x4 8MB | vpt 16MB | attn 16MB = 105.5MB
    ushort* qp   = (ushort*)d_ws;
    ushort* kp   = qp + SD;
    ushort* sc   = kp + SD;                        // [B][S][S]
    ushort* Wq16 = sc + (size_t)B * S * S;
    ushort* Wk16 = Wq16 + (size_t)D * D;
    ushort* Wv16 = Wk16 + (size_t)D * D;
    ushort* Wo16 = Wv16 + (size_t)D * D;
    ushort* vpt  = Wo16 + (size_t)D * D;           // per batch [D][S]
    ushort* attn = vpt + SD;                       // [B*S][D]

    // fp16 staging of q,k,v: dead after qkv_proj, so alias late-written regions.
    // qh/kh live in sc (written only by the score GEMM, after qkv_proj);
    // vh lives in attn (written only by the PV GEMM, after qkv_proj).
    ushort* qh = sc;                               // 16MB of sc's 33.5MB
    ushort* kh = sc + SD;                          // next 16MB of sc
    ushort* vh = attn;                             // 16MB

    dim3 blk(256);

    cvt_w<<<dim3(D * D / 2048, 4), blk, 0, stream>>>(Wq, Wk, Wv, Wo, Wq16, Wk16, Wv16, Wo16);
    cvt_qkv<<<dim3(SD / 2048, 3), blk, 0, stream>>>(q, k, v, qh, kh, vh);

    // qp/kp/vpt in one dispatch, both operands DMA-staged fp16
    qkv_proj<<<dim3(D / TILE, 192), blk, 0, stream>>>(
        qh, kh, vh, Wq16, Wk16, Wv16, bq, bk, bv, qp, kp, vpt);

    // sc = 0.125 * qp @ kp^T  (pre-scaled fp16 logits)
    gemm_nt<1, false, false><<<dim3(S / TILE, S / TILE, B), blk, 0, stream>>>(
        qp, (long long)S * D, D, kp, (long long)S * D, D,
        sc, (long long)S * S, S, nullptr, 0.125f, D);

    softmax_rows<<<dim3(B * S), blk, 0, stream>>>(sc);

    // attn = probs @ vp  (vp given as vpt rows)
    gemm_nt<1, false, false><<<dim3(D / TILE, S / TILE, B), blk, 0, stream>>>(
        sc, (long long)S * S, S, vpt, (long long)D * S, S,
        attn, (long long)S * D, D, nullptr, 1.0f, S);

    // out = attn @ Wo^T + bo  (fp32 out)
    gemm_nt<0, false, true><<<dim3(D / TILE, (B * S) / TILE, 1), blk, 0, stream>>>(
        attn, 0, D, Wo16, 0, D, out, 0, D, bo, 1.0f, D);
}

// Round 2
// 360.736 us; speedup vs baseline: 1.0609x; 1.0049x over previous
//
#include <hip/hip_runtime.h>
#include <hip/hip_fp16.h>

typedef __attribute__((ext_vector_type(8))) _Float16 half8;  // MFMA A/B frag (4 VGPRs)
typedef __attribute__((ext_vector_type(4))) float floatx4;   // MFMA C/D frag
typedef __attribute__((ext_vector_type(8))) ushort ushortx8; // 16B of fp16 bits

#define TILE 128
#define BK 64

__device__ inline ushort f2h(float f) {
    _Float16 h = (_Float16)f;
    ushort u; __builtin_memcpy(&u, &h, 2); return u;
}
__device__ inline float h2f(ushort u) {
    _Float16 h; __builtin_memcpy(&h, &u, 2);
    return (float)h;
}

// async 16B/lane global->LDS DMA; lds dest = base + lane*16 (implicit)
__device__ inline void async_copy16(const ushort* g, ushort* lds) {
    __builtin_amdgcn_global_load_lds(
        (const __attribute__((address_space(1))) void*)(const void*)g,
        (__attribute__((address_space(3))) void*)(void*)lds,
        16, 0, 0);
}

// XCD-aware remap (8 XCDs, flat id round-robin). Pure permutation.
__device__ inline void xcd_swizzle(int X, int YZ, int& bx, int& yz) {
    if ((YZ & 7) != 0) return;           // need YZ % 8 == 0
    const int flat = yz * X + bx;
    const int xcd  = flat & 7;
    const int t    = flat >> 3;
    const int rows = YZ >> 3;
    yz = xcd * rows + t / X;
    bx = t % X;
}

// ---------------------------------------------------------------------------
// 128x128 2-barrier core (kept for PV / out-proj whose grids are too small
// for the 256^2 template).
// ---------------------------------------------------------------------------
__device__ __forceinline__ void gemm_core(const ushort* __restrict__ A, int lda,
                                          const ushort* __restrict__ B, int ldb,
                                          int K, ushort* As, ushort* Bs,
                                          floatx4 acc[4][4])
{
    const int t    = threadIdx.x;
    const int lane = t & 63;
    const int wave = t >> 6;
    const int wr   = (wave >> 1) * 64;
    const int wc   = (wave & 1) * 64;
    const int lrow = lane & 15;
    const int srow = lane >> 3;                 // 0..7 within an 8-row DMA block
    const int gcol = ((lane & 7) ^ srow) * 8;   // global chunk, XOR-swizzled
    const int c0   = lane >> 4;                 // frag base chunk (k-quad)
    const int sw   = lane & 7;                  // frag row swizzle key

    for (int k0 = 0; k0 < K; k0 += BK) {
#pragma unroll
        for (int h = 0; h < 4; h++) {
            const int r0 = wave * 32 + h * 8;   // 8 rows per 1KB DMA
            async_copy16(A + (size_t)(r0 + srow) * lda + k0 + gcol, &As[r0 * 64]);
            async_copy16(B + (size_t)(r0 + srow) * ldb + k0 + gcol, &Bs[r0 * 64]);
        }
        __syncthreads();

#pragma unroll
        for (int step = 0; step < 2; step++) {
            half8 aF[4], bF[4];
            const int ch = ((4 * step + c0) ^ sw) * 8;
#pragma unroll
            for (int i = 0; i < 4; i++) {
                aF[i] = *(const half8*)(&As[(wr + i * 16 + lrow) * 64 + ch]);
                bF[i] = *(const half8*)(&Bs[(wc + i * 16 + lrow) * 64 + ch]);
            }
#pragma unroll
            for (int i = 0; i < 4; i++)
#pragma unroll
                for (int j = 0; j < 4; j++)
                    acc[i][j] = __builtin_amdgcn_mfma_f32_16x16x32_f16(aF[i], bF[j], acc[i][j], 0, 0, 0);
        }
        __syncthreads();
    }
}

// Epilogue (128^2). C/D layout: col=lane&15, row=(lane>>4)*4+reg.
template<int OM, bool TRANS, bool HB>
__device__ __forceinline__ void epilogue(floatx4 acc[4][4], void* Cb, int ldc,
                                         const float* bias, float scale)
{
    const int lane = threadIdx.x & 63;
    const int wave = threadIdx.x >> 6;
    const int wr = (wave >> 1) * 64, wc = (wave & 1) * 64;
    const int lrow = lane & 15, rq = (lane >> 4) * 4;
#pragma unroll
    for (int i = 0; i < 4; i++) {
#pragma unroll
        for (int j = 0; j < 4; j++) {
            const int n = wc + j * 16 + lrow;
            const float bv = HB ? bias[n] : 0.f;
#pragma unroll
            for (int r = 0; r < 4; r++) {
                const int m = wr + i * 16 + rq + r;
                const float val = acc[i][j][r] * scale + bv;
                const size_t idx = TRANS ? ((size_t)n * ldc + m) : ((size_t)m * ldc + n);
                if (OM == 0) ((float*)Cb)[idx] = val;
                else         ((ushort*)Cb)[idx] = f2h(val);
            }
        }
    }
}

template<int OM, bool TRANS, bool HB>
__global__ __launch_bounds__(256)
void gemm_nt(const ushort* __restrict__ A, long long batchA, int lda,
             const ushort* __restrict__ B, long long batchB, int ldb,
             void* __restrict__ C, long long batchC, int ldc,
             const float* __restrict__ bias, float scale, int K)
{
    __shared__ ushort As[TILE * BK];
    __shared__ ushort Bs[TILE * BK];

    int bx = blockIdx.x;
    int yz = blockIdx.y + gridDim.y * blockIdx.z;
    xcd_swizzle(gridDim.x, gridDim.y * gridDim.z, bx, yz);
    const int by = yz % gridDim.y;
    const int bz = yz / gridDim.y;
    const int tileM = by * TILE, tileN = bx * TILE;

    floatx4 acc[4][4];
#pragma unroll
    for (int i = 0; i < 4; i++)
#pragma unroll
        for (int j = 0; j < 4; j++) acc[i][j] = (floatx4){0.f, 0.f, 0.f, 0.f};

    gemm_core(A + (size_t)bz * batchA + (size_t)tileM * lda, lda,
              B + (size_t)bz * batchB + (size_t)tileN * ldb, ldb,
              K, As, Bs, acc);

    const size_t coff = TRANS ? ((size_t)tileN * ldc + tileM) : ((size_t)tileM * ldc + tileN);
    void* Cb = (OM == 0) ? (void*)((float*)C + (size_t)bz * batchC + coff)
                         : (void*)((ushort*)C + (size_t)bz * batchC + coff);
    epilogue<OM, TRANS, HB>(acc, Cb, ldc, HB ? bias + tileN : nullptr, scale);
}

// ---------------------------------------------------------------------------
// 256x256 8-phase core (T3+T4+T5). BK=64 split in K-halves (256 rows x 32 K
// = 16 KB each). 512 threads = 8 waves (2M x 4N); per-wave output 128x64.
// LDS 128 KiB: [2 buf][2 ks-half][256*32] per operand.
//
// Per K-tile, 4 phases; stage schedule at tile T issues:
//   ph0 -> (T+1).Bh1   ph1 -> (T+2).Ah0   ph2 -> (T+2).Bh0   ph3 -> (T+2).Ah1
// Each stage targets a region whose last reads completed at a preceding
// barrier (Ah0 read only at ph0, Bh0 at ph0, Ah1/Bh1 at ph2) -> deterministic.
// Counted vmcnt(6) once per K-tile (3 half-tiles = 6 loads in flight);
// vmcnt(0) only at T = NT-2 (tail drain). Never drains in steady state.
//
// LDS swizzle: row r of a 32-elem K-half stores chunk c (8 elems) at slot
// c ^ ((r>>1)&3); read side uses slot = (lane>>4) ^ ((lane>>1)&3): 16-lane
// frag reads spread 2-way per bank group (free, m136). DMA pre-swizzles the
// global source column: col = 8*((lane&3) ^ ((lane>>3)&3)), 64B/row segments.
// ---------------------------------------------------------------------------
__device__ __forceinline__ void stage_half256(const ushort* g, int ld, ushort* ldsHalf,
                                              int wave, int lane)
{
    const int col = ((lane & 3) ^ ((lane >> 3) & 3)) * 8;
    const int rl  = lane >> 2;                  // 0..15 row within 16-row block
#pragma unroll
    for (int q = 0; q < 2; q++) {
        const int blk = q * 8 + wave;           // 16-row block index (0..15)
        async_copy16(g + (size_t)(blk * 16 + rl) * ld + col, ldsHalf + blk * 512);
    }
}

#define MFMA16(aF, bF, j0) \
    _Pragma("unroll") \
    for (int i = 0; i < 8; i++) { \
        acc[i][j0]     = __builtin_amdgcn_mfma_f32_16x16x32_f16(aF[i], bF[j0],     acc[i][j0],     0, 0, 0); \
        acc[i][j0 + 1] = __builtin_amdgcn_mfma_f32_16x16x32_f16(aF[i], bF[j0 + 1], acc[i][j0 + 1], 0, 0, 0); \
    }

__device__ __forceinline__ void gemm_core256(const ushort* __restrict__ A, int lda,
                                             const ushort* __restrict__ B, int ldb,
                                             int K, ushort* As, ushort* Bs,
                                             floatx4 acc[8][4])
{
    const int t    = threadIdx.x;
    const int lane = t & 63;
    const int wave = t >> 6;
    const int wm   = wave >> 2;                 // 0..1
    const int wn   = wave & 3;                  // 0..3
    const int lrow = lane & 15;
    const int slot8 = (((lane >> 4) ^ ((lane >> 1) & 3))) * 8;
    const int NT   = K / 64;

    // half base: operand LDS + ((buf*2 + ks) * 8192)
#define AH(T, ks) (As + ((((T) & 1) * 2 + (ks)) * 8192))
#define BH(T, ks) (Bs + ((((T) & 1) * 2 + (ks)) * 8192))

    // prologue: T0.{Ah0,Bh0,Ah1,Bh1}, T1.{Ah0,Bh0,Ah1}  (7 halves = 14 loads)
    stage_half256(A +  0, lda, AH(0, 0), wave, lane);
    stage_half256(B +  0, ldb, BH(0, 0), wave, lane);
    stage_half256(A + 32, lda, AH(0, 1), wave, lane);
    stage_half256(B + 32, ldb, BH(0, 1), wave, lane);
    stage_half256(A + 64, lda, AH(1, 0), wave, lane);
    stage_half256(B + 64, ldb, BH(1, 0), wave, lane);
    stage_half256(A + 96, lda, AH(1, 1), wave, lane);
    asm volatile("s_waitcnt vmcnt(6)" ::: "memory");   // T0 fully staged
    __builtin_amdgcn_s_barrier();

    half8 aF[8], bF[4];

    for (int T = 0; T < NT; T++) {
        // ---- ph0: ds_read ks=0 (8 A + 4 B), stage (T+1).Bh1, MFMA j0-1 ks0
        {
            const ushort* Ac = AH(T, 0) + (wm * 128 + lrow) * 32 + slot8;
            const ushort* Bc = BH(T, 0) + (wn * 64  + lrow) * 32 + slot8;
#pragma unroll
            for (int i = 0; i < 8; i++) aF[i] = *(const half8*)(Ac + i * 512);
#pragma unroll
            for (int j = 0; j < 4; j++) bF[j] = *(const half8*)(Bc + j * 512);
        }
        if (T + 1 < NT) stage_half256(B + (size_t)(T + 1) * 64 + 32, ldb, BH(T + 1, 1), wave, lane);
        __builtin_amdgcn_s_barrier();
        asm volatile("s_waitcnt lgkmcnt(0)" ::: "memory");
        __builtin_amdgcn_s_setprio(1);
        MFMA16(aF, bF, 0)
        __builtin_amdgcn_s_setprio(0);
        __builtin_amdgcn_s_barrier();

        // ---- ph1: stage (T+2).Ah0, MFMA j2-3 ks0
        if (T + 2 < NT) stage_half256(A + (size_t)(T + 2) * 64, lda, AH(T + 2, 0), wave, lane);
        __builtin_amdgcn_s_barrier();
        __builtin_amdgcn_s_setprio(1);
        MFMA16(aF, bF, 2)
        __builtin_amdgcn_s_setprio(0);
        __builtin_amdgcn_s_barrier();

        // ---- ph2: ds_read ks=1, stage (T+2).Bh0, MFMA j0-1 ks1
        {
            const ushort* Ac = AH(T, 1) + (wm * 128 + lrow) * 32 + slot8;
            const ushort* Bc = BH(T, 1) + (wn * 64  + lrow) * 32 + slot8;
#pragma unroll
            for (int i = 0; i < 8; i++) aF[i] = *(const half8*)(Ac + i * 512);
#pragma unroll
            for (int j = 0; j < 4; j++) bF[j] = *(const half8*)(Bc + j * 512);
        }
        if (T + 2 < NT) stage_half256(B + (size_t)(T + 2) * 64, ldb, BH(T + 2, 0), wave, lane);
        __builtin_amdgcn_s_barrier();
        asm volatile("s_waitcnt lgkmcnt(0)" ::: "memory");
        __builtin_amdgcn_s_setprio(1);
        MFMA16(aF, bF, 0)
        __builtin_amdgcn_s_setprio(0);
        __builtin_amdgcn_s_barrier();

        // ---- ph3: stage (T+2).Ah1, MFMA j2-3 ks1, counted vmcnt
        if (T + 2 < NT) stage_half256(A + (size_t)(T + 2) * 64 + 32, lda, AH(T + 2, 1), wave, lane);
        __builtin_amdgcn_s_barrier();
        __builtin_amdgcn_s_setprio(1);
        MFMA16(aF, bF, 2)
        __builtin_amdgcn_s_setprio(0);
        if (T == NT - 2) { asm volatile("s_waitcnt vmcnt(0)" ::: "memory"); }
        else             { asm volatile("s_waitcnt vmcnt(6)" ::: "memory"); }
        __builtin_amdgcn_s_barrier();
    }
#undef AH
#undef BH
}

// Epilogue (256^2): per-wave 128x64 tile; same C/D frag mapping.
template<int OM, bool TRANS, bool HB>
__device__ __forceinline__ void epilogue256(floatx4 acc[8][4], void* Cb, int ldc,
                                            const float* bias, float scale)
{
    const int lane = threadIdx.x & 63;
    const int wave = threadIdx.x >> 6;
    const int wr = (wave >> 2) * 128, wc = (wave & 3) * 64;
    const int lrow = lane & 15, rq = (lane >> 4) * 4;
#pragma unroll
    for (int i = 0; i < 8; i++) {
#pragma unroll
        for (int j = 0; j < 4; j++) {
            const int n = wc + j * 16 + lrow;
            const float bv = HB ? bias[n] : 0.f;
#pragma unroll
            for (int r = 0; r < 4; r++) {
                const int m = wr + i * 16 + rq + r;
                const float val = acc[i][j][r] * scale + bv;
                const size_t idx = TRANS ? ((size_t)n * ldc + m) : ((size_t)m * ldc + n);
                if (OM == 0) ((float*)Cb)[idx] = val;
                else         ((ushort*)Cb)[idx] = f2h(val);
            }
        }
    }
}

template<int OM, bool TRANS, bool HB>
__global__ __launch_bounds__(512, 2)
void gemm_nt256(const ushort* __restrict__ A, long long batchA, int lda,
                const ushort* __restrict__ B, long long batchB, int ldb,
                void* __restrict__ C, long long batchC, int ldc,
                const float* __restrict__ bias, float scale, int K)
{
    __shared__ ushort As[4 * 8192];   // 64 KB
    __shared__ ushort Bs[4 * 8192];   // 64 KB

    int bx = blockIdx.x;
    int yz = blockIdx.y + gridDim.y * blockIdx.z;
    xcd_swizzle(gridDim.x, gridDim.y * gridDim.z, bx, yz);
    const int by = yz % gridDim.y;
    const int bz = yz / gridDim.y;
    const int tileM = by * 256, tileN = bx * 256;

    floatx4 acc[8][4];
#pragma unroll
    for (int i = 0; i < 8; i++)
#pragma unroll
        for (int j = 0; j < 4; j++) acc[i][j] = (floatx4){0.f, 0.f, 0.f, 0.f};

    gemm_core256(A + (size_t)bz * batchA + (size_t)tileM * lda, lda,
                 B + (size_t)bz * batchB + (size_t)tileN * ldb, ldb,
                 K, As, Bs, acc);

    const size_t coff = TRANS ? ((size_t)tileN * ldc + tileM) : ((size_t)tileM * ldc + tileN);
    void* Cb = (OM == 0) ? (void*)((float*)C + (size_t)bz * batchC + coff)
                         : (void*)((ushort*)C + (size_t)bz * batchC + coff);
    epilogue256<OM, TRANS, HB>(acc, Cb, ldc, HB ? bias + tileN : nullptr, scale);
}

// Fused Q/K/V projections on the 8-phase 256^2 core. logical grid (4, 96):
//  y in [0,32): qp = q @ Wq^T + bq
//  y in [32,64): kp = k @ Wk^T + bk
//  y in [64,96): vpt_b = (v_b @ Wv^T + bv)^T   (b = (y-64)/8)
__global__ __launch_bounds__(512, 2)
void qkv_proj256(const ushort* __restrict__ q, const ushort* __restrict__ k,
                 const ushort* __restrict__ v,
                 const ushort* __restrict__ Wq, const ushort* __restrict__ Wk,
                 const ushort* __restrict__ Wv,
                 const float* __restrict__ bq, const float* __restrict__ bk,
                 const float* __restrict__ bv,
                 ushort* __restrict__ qp, ushort* __restrict__ kp,
                 ushort* __restrict__ vpt)
{
    __shared__ ushort As[4 * 8192];
    __shared__ ushort Bs[4 * 8192];
    const int D = 1024, S = 2048;

    int bx = blockIdx.x, y = blockIdx.y;
    xcd_swizzle(4, 96, bx, y);
    const int tileN = bx * 256;

    floatx4 acc[8][4];
#pragma unroll
    for (int i = 0; i < 8; i++)
#pragma unroll
        for (int j = 0; j < 4; j++) acc[i][j] = (floatx4){0.f, 0.f, 0.f, 0.f};

    if (y < 64) {            // block-uniform branch
        const bool isQ = (y < 32);
        const int my = isQ ? y : y - 32;
        const ushort* A = (isQ ? q : k) + (size_t)my * 256 * D;
        const ushort* W = (isQ ? Wq : Wk) + (size_t)tileN * D;
        gemm_core256(A, D, W, D, D, As, Bs, acc);
        ushort* Cb = (isQ ? qp : kp) + (size_t)my * 256 * D + tileN;
        epilogue256<1, false, true>(acc, Cb, D, (isQ ? bq : bk) + tileN, 1.0f);
    } else {
        const int yy = y - 64;
        const int bz = yy >> 3, my = yy & 7;
        const ushort* A = v + ((size_t)bz * S + (size_t)my * 256) * D;
        gemm_core256(A, D, Wv + (size_t)tileN * D, D, D, As, Bs, acc);
        ushort* Cb = vpt + (size_t)bz * D * S + (size_t)tileN * S + (size_t)my * 256;
        epilogue256<1, true, true>(acc, Cb, S, bv + tileN, 1.0f);
    }
}

// fp32 -> fp16 for the 4 weight matrices (D*D each); grid (512, 4)
__global__ __launch_bounds__(256)
void cvt_w(const float* __restrict__ w0, const float* __restrict__ w1,
           const float* __restrict__ w2, const float* __restrict__ w3,
           ushort* __restrict__ o0, ushort* __restrict__ o1,
           ushort* __restrict__ o2, ushort* __restrict__ o3)
{
    const float* src; ushort* dst;
    switch (blockIdx.y) {
        case 0: src = w0; dst = o0; break;
        case 1: src = w1; dst = o1; break;
        case 2: src = w2; dst = o2; break;
        default: src = w3; dst = o3; break;
    }
    const size_t i = ((size_t)blockIdx.x * 256 + threadIdx.x) * 8;
    floatx4 f0 = *(const floatx4*)(src + i);
    floatx4 f1 = *(const floatx4*)(src + i + 4);
    ushortx8 u;
    u[0] = f2h(f0.x); u[1] = f2h(f0.y); u[2] = f2h(f0.z); u[3] = f2h(f0.w);
    u[4] = f2h(f1.x); u[5] = f2h(f1.y); u[6] = f2h(f1.z); u[7] = f2h(f1.w);
    *(ushortx8*)(dst + i) = u;
}

// fp32 -> fp16 for q,k,v activations (B*S*D each); grid (4096, 3).
__global__ __launch_bounds__(256)
void cvt_qkv(const float* __restrict__ q, const float* __restrict__ k,
             const float* __restrict__ v,
             ushort* __restrict__ qh, ushort* __restrict__ kh,
             ushort* __restrict__ vh)
{
    const float* src; ushort* dst;
    switch (blockIdx.y) {
        case 0: src = q; dst = qh; break;
        case 1: src = k; dst = kh; break;
        default: src = v; dst = vh; break;
    }
    const size_t i = ((size_t)blockIdx.x * 256 + threadIdx.x) * 8;
    floatx4 f0 = *(const floatx4*)(src + i);
    floatx4 f1 = *(const floatx4*)(src + i + 4);
    ushortx8 u;
    u[0] = f2h(f0.x); u[1] = f2h(f0.y); u[2] = f2h(f0.z); u[3] = f2h(f0.w);
    u[4] = f2h(f1.x); u[5] = f2h(f1.y); u[6] = f2h(f1.z); u[7] = f2h(f1.w);
    *(ushortx8*)(dst + i) = u;
}

// Row softmax over S=2048 pre-scaled fp16 logits; fp32 math; fp16 probs in place.
__global__ __launch_bounds__(256)
void softmax_rows(ushort* __restrict__ scores)
{
    const int S = 2048;
    ushort* srow = scores + (size_t)blockIdx.x * S;
    const int t    = threadIdx.x;
    const int lane = t & 63;
    const int w    = t >> 6;

    ushortx8 raw = *(const ushortx8*)(srow + t * 8);
    float l[8];
#pragma unroll
    for (int i = 0; i < 8; i++) l[i] = h2f(raw[i]);

    float m = l[0];
#pragma unroll
    for (int i = 1; i < 8; i++) m = fmaxf(m, l[i]);
#pragma unroll
    for (int off = 32; off >= 1; off >>= 1) m = fmaxf(m, __shfl_down(m, off));

    __shared__ float redm[4], reds[4];
    if (lane == 0) redm[w] = m;
    __syncthreads();
    m = fmaxf(fmaxf(redm[0], redm[1]), fmaxf(redm[2], redm[3]));

    float e[8], s = 0.f;
#pragma unroll
    for (int i = 0; i < 8; i++) { e[i] = __expf(l[i] - m); s += e[i]; }
#pragma unroll
    for (int off = 32; off >= 1; off >>= 1) s += __shfl_down(s, off);
    if (lane == 0) reds[w] = s;
    __syncthreads();
    s = reds[0] + reds[1] + reds[2] + reds[3];
    const float inv = 1.f / s;

    ushortx8 o;
#pragma unroll
    for (int i = 0; i < 8; i++) o[i] = f2h(e[i] * inv);
    *(ushortx8*)(srow + t * 8) = o;
}

extern "C" void kernel_launch(void* const* d_in, const int* in_sizes, int n_in,
                              void* d_out, int out_size, void* d_ws, size_t ws_size,
                              hipStream_t stream)
{
    const int B = 4, S = 2048, D = 1024;
    const size_t SD = (size_t)B * S * D;   // 8M elems
    const float* q  = (const float*)d_in[0];
    const float* k  = (const float*)d_in[1];
    const float* v  = (const float*)d_in[2];
    const float* Wq = (const float*)d_in[3];
    const float* bq = (const float*)d_in[4];
    const float* Wk = (const float*)d_in[5];
    const float* bk = (const float*)d_in[6];
    const float* Wv = (const float*)d_in[7];
    const float* bv = (const float*)d_in[8];
    const float* Wo = (const float*)d_in[9];
    const float* bo = (const float*)d_in[10];
    float* out = (float*)d_out;

    // ws (ushort): qp 16MB | kp 16MB | sc 33.5MB | W16 x4 8MB | vpt 16MB | attn 16MB
    ushort* qp   = (ushort*)d_ws;
    ushort* kp   = qp + SD;
    ushort* sc   = kp + SD;                        // [B][S][S]
    ushort* Wq16 = sc + (size_t)B * S * S;
    ushort* Wk16 = Wq16 + (size_t)D * D;
    ushort* Wv16 = Wk16 + (size_t)D * D;
    ushort* Wo16 = Wv16 + (size_t)D * D;
    ushort* vpt  = Wo16 + (size_t)D * D;           // per batch [D][S]
    ushort* attn = vpt + SD;                       // [B*S][D]

    // fp16 staging of q,k,v: dead after qkv_proj, so alias late-written regions.
    ushort* qh = sc;                               // 16MB of sc's 33.5MB
    ushort* kh = sc + SD;                          // next 16MB of sc
    ushort* vh = attn;                             // 16MB

    dim3 blk(256);
    dim3 blk512(512);

    cvt_w<<<dim3(D * D / 2048, 4), blk, 0, stream>>>(Wq, Wk, Wv, Wo, Wq16, Wk16, Wv16, Wo16);
    cvt_qkv<<<dim3(SD / 2048, 3), blk, 0, stream>>>(q, k, v, qh, kh, vh);

    // qp/kp/vpt in one dispatch, 8-phase 256^2 core
    qkv_proj256<<<dim3(D / 256, 96), blk512, 0, stream>>>(
        qh, kh, vh, Wq16, Wk16, Wv16, bq, bk, bv, qp, kp, vpt);

    // sc = 0.125 * qp @ kp^T  (pre-scaled fp16 logits), 8-phase 256^2 core
    gemm_nt256<1, false, false><<<dim3(S / 256, S / 256, B), blk512, 0, stream>>>(
        qp, (long long)S * D, D, kp, (long long)S * D, D,
        sc, (long long)S * S, S, nullptr, 0.125f, D);

    softmax_rows<<<dim3(B * S), blk, 0, stream>>>(sc);

    // attn = probs @ vp  (vp given as vpt rows) — 128^2 core (grid too small for 256^2)
    gemm_nt<1, false, false><<<dim3(D / TILE, S / TILE, B), blk, 0, stream>>>(
        sc, (long long)S * S, S, vpt, (long long)D * S, S,
        attn, (long long)S * D, D, nullptr, 1.0f, S);

    // out = attn @ Wo^T + bo  (fp32 out) — 128^2 core
    gemm_nt<0, false, true><<<dim3(D / TILE, (B * S) / TILE, 1), blk, 0, stream>>>(
        attn, 0, D, Wo16, 0, D, out, 0, D, bo, 1.0f, D);
}

// Round 5
// 351.749 us; speedup vs baseline: 1.0880x; 1.0256x over previous
//
#include <hip/hip_runtime.h>
#include <hip/hip_fp16.h>

typedef __attribute__((ext_vector_type(8))) _Float16 half8;  // MFMA A/B frag (4 VGPRs)
typedef __attribute__((ext_vector_type(4))) float floatx4;   // MFMA C/D frag
typedef __attribute__((ext_vector_type(8))) ushort ushortx8; // 16B of fp16 bits

#define TILE 128
#define BK 64

__device__ inline ushort f2h(float f) {
    _Float16 h = (_Float16)f;
    ushort u; __builtin_memcpy(&u, &h, 2); return u;
}
__device__ inline float h2f(ushort u) {
    _Float16 h; __builtin_memcpy(&h, &u, 2);
    return (float)h;
}

// async 16B/lane global->LDS DMA; lds dest = base + lane*16 (implicit)
__device__ inline void async_copy16(const ushort* g, ushort* lds) {
    __builtin_amdgcn_global_load_lds(
        (const __attribute__((address_space(1))) void*)(const void*)g,
        (__attribute__((address_space(3))) void*)(void*)lds,
        16, 0, 0);
}

// XCD-aware remap (8 XCDs, flat id round-robin). Pure permutation.
__device__ inline void xcd_swizzle(int X, int YZ, int& bx, int& yz) {
    if ((YZ & 7) != 0) return;           // need YZ % 8 == 0
    const int flat = yz * X + bx;
    const int xcd  = flat & 7;
    const int t    = flat >> 3;
    const int rows = YZ >> 3;
    yz = xcd * rows + t / X;
    bx = t % X;
}

// ---------------------------------------------------------------------------
// 128x128 2-barrier core (kept for PV / out-proj whose grids are too small
// for the 256^2 template).
// ---------------------------------------------------------------------------
__device__ __forceinline__ void gemm_core(const ushort* __restrict__ A, int lda,
                                          const ushort* __restrict__ B, int ldb,
                                          int K, ushort* As, ushort* Bs,
                                          floatx4 acc[4][4])
{
    const int t    = threadIdx.x;
    const int lane = t & 63;
    const int wave = t >> 6;
    const int wr   = (wave >> 1) * 64;
    const int wc   = (wave & 1) * 64;
    const int lrow = lane & 15;
    const int srow = lane >> 3;                 // 0..7 within an 8-row DMA block
    const int gcol = ((lane & 7) ^ srow) * 8;   // global chunk, XOR-swizzled
    const int c0   = lane >> 4;                 // frag base chunk (k-quad)
    const int sw   = lane & 7;                  // frag row swizzle key

    for (int k0 = 0; k0 < K; k0 += BK) {
#pragma unroll
        for (int h = 0; h < 4; h++) {
            const int r0 = wave * 32 + h * 8;   // 8 rows per 1KB DMA
            async_copy16(A + (size_t)(r0 + srow) * lda + k0 + gcol, &As[r0 * 64]);
            async_copy16(B + (size_t)(r0 + srow) * ldb + k0 + gcol, &Bs[r0 * 64]);
        }
        __syncthreads();

#pragma unroll
        for (int step = 0; step < 2; step++) {
            half8 aF[4], bF[4];
            const int ch = ((4 * step + c0) ^ sw) * 8;
#pragma unroll
            for (int i = 0; i < 4; i++) {
                aF[i] = *(const half8*)(&As[(wr + i * 16 + lrow) * 64 + ch]);
                bF[i] = *(const half8*)(&Bs[(wc + i * 16 + lrow) * 64 + ch]);
            }
#pragma unroll
            for (int i = 0; i < 4; i++)
#pragma unroll
                for (int j = 0; j < 4; j++)
                    acc[i][j] = __builtin_amdgcn_mfma_f32_16x16x32_f16(aF[i], bF[j], acc[i][j], 0, 0, 0);
        }
        __syncthreads();
    }
}

// Epilogue (128^2). C/D layout: col=lane&15, row=(lane>>4)*4+reg.
template<int OM, bool TRANS, bool HB>
__device__ __forceinline__ void epilogue(floatx4 acc[4][4], void* Cb, int ldc,
                                         const float* bias, float scale)
{
    const int lane = threadIdx.x & 63;
    const int wave = threadIdx.x >> 6;
    const int wr = (wave >> 1) * 64, wc = (wave & 1) * 64;
    const int lrow = lane & 15, rq = (lane >> 4) * 4;
#pragma unroll
    for (int i = 0; i < 4; i++) {
#pragma unroll
        for (int j = 0; j < 4; j++) {
            const int n = wc + j * 16 + lrow;
            const float bv = HB ? bias[n] : 0.f;
#pragma unroll
            for (int r = 0; r < 4; r++) {
                const int m = wr + i * 16 + rq + r;
                const float val = acc[i][j][r] * scale + bv;
                const size_t idx = TRANS ? ((size_t)n * ldc + m) : ((size_t)m * ldc + n);
                if (OM == 0) ((float*)Cb)[idx] = val;
                else         ((ushort*)Cb)[idx] = f2h(val);
            }
        }
    }
}

template<int OM, bool TRANS, bool HB>
__global__ __launch_bounds__(256)
void gemm_nt(const ushort* __restrict__ A, long long batchA, int lda,
             const ushort* __restrict__ B, long long batchB, int ldb,
             void* __restrict__ C, long long batchC, int ldc,
             const float* __restrict__ bias, float scale, int K)
{
    __shared__ ushort As[TILE * BK];
    __shared__ ushort Bs[TILE * BK];

    int bx = blockIdx.x;
    int yz = blockIdx.y + gridDim.y * blockIdx.z;
    xcd_swizzle(gridDim.x, gridDim.y * gridDim.z, bx, yz);
    const int by = yz % gridDim.y;
    const int bz = yz / gridDim.y;
    const int tileM = by * TILE, tileN = bx * TILE;

    floatx4 acc[4][4];
#pragma unroll
    for (int i = 0; i < 4; i++)
#pragma unroll
        for (int j = 0; j < 4; j++) acc[i][j] = (floatx4){0.f, 0.f, 0.f, 0.f};

    gemm_core(A + (size_t)bz * batchA + (size_t)tileM * lda, lda,
              B + (size_t)bz * batchB + (size_t)tileN * ldb, ldb,
              K, As, Bs, acc);

    const size_t coff = TRANS ? ((size_t)tileN * ldc + tileM) : ((size_t)tileM * ldc + tileN);
    void* Cb = (OM == 0) ? (void*)((float*)C + (size_t)bz * batchC + coff)
                         : (void*)((ushort*)C + (size_t)bz * batchC + coff);
    epilogue<OM, TRANS, HB>(acc, Cb, ldc, HB ? bias + tileN : nullptr, scale);
}

// ---------------------------------------------------------------------------
// 256x256 pipelined core, v2.1. BK=64 split in K-halves (256 rows x 32 K =
// 16 KB each). 512 threads = 8 waves (2M x 4N); per-wave output 128x64.
// LDS 128 KiB: [2 buf][2 ks-half][256*32] per operand.
//
// 2 phases per K-tile, ds_reads pipelined ONE PHASE AHEAD so MFMA never
// waits on LDS latency:
//   P0: stage (T+2)h0 (4 loads); read FS_b<-(T,ks1) (12 b128);
//       lgkmcnt(12) [FS_a ready]; 32 MFMA(FS_a); lgkmcnt(0) [drain FS_b,
//       hidden under MFMA]; vmcnt(4) [publish tile T+1]; barrier.
//   P1: stage (T+2)h1; read FS_a<-(T+1,ks0); lgkmcnt(12) [FS_b ready];
//       32 MFMA(FS_b); lgkmcnt(0); barrier.
// Safety: every stage overwrites a region whose readers drained at the
// previous phase's lgkmcnt(0)+barrier. vmcnt counted in loads (4/phase).
// TAIL FIX (v2.1): at T==NT-2, P0 stages nothing, so 8 loads are
// outstanding ((NT-1)h0 + (NT-1)h1) and vmcnt(4) only publishes h0 —
// the FS_b read of (NT-1,ks1) at T==NT-1 would race its DMA. Use
// vmcnt(0) there (one-time full drain, last tile only).
// ---------------------------------------------------------------------------
__device__ __forceinline__ void stage_half256(const ushort* g, int ld, ushort* ldsHalf,
                                              int wave, int lane)
{
    const int col = ((lane & 3) ^ ((lane >> 3) & 3)) * 8;
    const int rl  = lane >> 2;                  // 0..15 row within 16-row block
#pragma unroll
    for (int q = 0; q < 2; q++) {
        const int blk = q * 8 + wave;           // 16-row block index (0..15)
        async_copy16(g + (size_t)(blk * 16 + rl) * ld + col, ldsHalf + blk * 512);
    }
}

__device__ __forceinline__ void mfma32(const half8 (&aF)[8], const half8 (&bF)[4],
                                       floatx4 (&acc)[8][4])
{
#pragma unroll
    for (int i = 0; i < 8; i++)
#pragma unroll
        for (int j = 0; j < 4; j++)
            acc[i][j] = __builtin_amdgcn_mfma_f32_16x16x32_f16(aF[i], bF[j], acc[i][j], 0, 0, 0);
}

__device__ __forceinline__ void gemm_core256(const ushort* __restrict__ A, int lda,
                                             const ushort* __restrict__ B, int ldb,
                                             int K, ushort* As, ushort* Bs,
                                             floatx4 (&acc)[8][4])
{
    const int t    = threadIdx.x;
    const int lane = t & 63;
    const int wave = t >> 6;
    const int wm   = wave >> 2;                 // 0..1
    const int wn   = wave & 3;                  // 0..3
    const int lrow = lane & 15;
    const int slot8 = ((lane >> 4) ^ ((lane >> 1) & 3)) * 8;
    const int NT   = K / 64;

#define AH(T, ks) (As + ((((T) & 1) * 2 + (ks)) * 8192))
#define BH(T, ks) (Bs + ((((T) & 1) * 2 + (ks)) * 8192))

    // prologue: stage tiles 0 and 1 fully (16 loads)
    stage_half256(A +  0, lda, AH(0, 0), wave, lane);
    stage_half256(B +  0, ldb, BH(0, 0), wave, lane);
    stage_half256(A + 32, lda, AH(0, 1), wave, lane);
    stage_half256(B + 32, ldb, BH(0, 1), wave, lane);
    stage_half256(A + 64, lda, AH(1, 0), wave, lane);
    stage_half256(B + 64, ldb, BH(1, 0), wave, lane);
    stage_half256(A + 96, lda, AH(1, 1), wave, lane);
    stage_half256(B + 96, ldb, BH(1, 1), wave, lane);
    asm volatile("s_waitcnt vmcnt(8)" ::: "memory");   // tile 0 landed
    __builtin_amdgcn_s_barrier();

    half8 aA[8], bA[4];   // FS_a: ks0 frags
    half8 aB[8], bB[4];   // FS_b: ks1 frags

    // FS_a <- (0, ks0); drain + publish before loop (T0.P0 stages overwrite h0)
    {
        const ushort* Ac = AH(0, 0) + (wm * 128 + lrow) * 32 + slot8;
        const ushort* Bc = BH(0, 0) + (wn * 64  + lrow) * 32 + slot8;
#pragma unroll
        for (int i = 0; i < 8; i++) aA[i] = *(const half8*)(Ac + i * 512);
#pragma unroll
        for (int j = 0; j < 4; j++) bA[j] = *(const half8*)(Bc + j * 512);
    }
    asm volatile("s_waitcnt lgkmcnt(0)" ::: "memory");
    __builtin_amdgcn_s_barrier();

    for (int T = 0; T < NT; T++) {
        // ---------------- P0 (MFMA ks0) ----------------
        if (T + 2 < NT) {
            stage_half256(A + (size_t)(T + 2) * 64, lda, AH(T + 2, 0), wave, lane);
            stage_half256(B + (size_t)(T + 2) * 64, ldb, BH(T + 2, 0), wave, lane);
        }
        {   // FS_b <- (T, ks1)
            const ushort* Ac = AH(T, 1) + (wm * 128 + lrow) * 32 + slot8;
            const ushort* Bc = BH(T, 1) + (wn * 64  + lrow) * 32 + slot8;
#pragma unroll
            for (int i = 0; i < 8; i++) aB[i] = *(const half8*)(Ac + i * 512);
#pragma unroll
            for (int j = 0; j < 4; j++) bB[j] = *(const half8*)(Bc + j * 512);
        }
        asm volatile("s_waitcnt lgkmcnt(12)" ::: "memory");  // FS_a ready
        __builtin_amdgcn_sched_barrier(0);
        __builtin_amdgcn_s_setprio(1);
        mfma32(aA, bA, acc);
        __builtin_amdgcn_s_setprio(0);
        asm volatile("s_waitcnt lgkmcnt(0)" ::: "memory");   // FS_b drained (under MFMA)
        if (T == NT - 2) { asm volatile("s_waitcnt vmcnt(0)" ::: "memory"); }  // tail: publish (NT-1)h1 too
        else             { asm volatile("s_waitcnt vmcnt(4)" ::: "memory"); }  // publish tile T+1
        __builtin_amdgcn_s_barrier();

        // ---------------- P1 (MFMA ks1) ----------------
        if (T + 2 < NT) {
            stage_half256(A + (size_t)(T + 2) * 64 + 32, lda, AH(T + 2, 1), wave, lane);
            stage_half256(B + (size_t)(T + 2) * 64 + 32, ldb, BH(T + 2, 1), wave, lane);
        }
        if (T + 1 < NT) {   // FS_a <- (T+1, ks0)
            const ushort* Ac = AH(T + 1, 0) + (wm * 128 + lrow) * 32 + slot8;
            const ushort* Bc = BH(T + 1, 0) + (wn * 64  + lrow) * 32 + slot8;
#pragma unroll
            for (int i = 0; i < 8; i++) aA[i] = *(const half8*)(Ac + i * 512);
#pragma unroll
            for (int j = 0; j < 4; j++) bA[j] = *(const half8*)(Bc + j * 512);
        }
        asm volatile("s_waitcnt lgkmcnt(12)" ::: "memory");  // FS_b ready
        __builtin_amdgcn_sched_barrier(0);
        __builtin_amdgcn_s_setprio(1);
        mfma32(aB, bB, acc);
        __builtin_amdgcn_s_setprio(0);
        asm volatile("s_waitcnt lgkmcnt(0)" ::: "memory");   // FS_a drained
        __builtin_amdgcn_s_barrier();
    }
#undef AH
#undef BH
}

// Epilogue (256^2): per-wave 128x64 tile; same C/D frag mapping.
template<int OM, bool TRANS, bool HB>
__device__ __forceinline__ void epilogue256(floatx4 (&acc)[8][4], void* Cb, int ldc,
                                            const float* bias, float scale)
{
    const int lane = threadIdx.x & 63;
    const int wave = threadIdx.x >> 6;
    const int wr = (wave >> 2) * 128, wc = (wave & 3) * 64;
    const int lrow = lane & 15, rq = (lane >> 4) * 4;
#pragma unroll
    for (int i = 0; i < 8; i++) {
#pragma unroll
        for (int j = 0; j < 4; j++) {
            const int n = wc + j * 16 + lrow;
            const float bv = HB ? bias[n] : 0.f;
#pragma unroll
            for (int r = 0; r < 4; r++) {
                const int m = wr + i * 16 + rq + r;
                const float val = acc[i][j][r] * scale + bv;
                const size_t idx = TRANS ? ((size_t)n * ldc + m) : ((size_t)m * ldc + n);
                if (OM == 0) ((float*)Cb)[idx] = val;
                else         ((ushort*)Cb)[idx] = f2h(val);
            }
        }
    }
}

template<int OM, bool TRANS, bool HB>
__global__ __launch_bounds__(512, 2)
void gemm_nt256(const ushort* __restrict__ A, long long batchA, int lda,
                const ushort* __restrict__ B, long long batchB, int ldb,
                void* __restrict__ C, long long batchC, int ldc,
                const float* __restrict__ bias, float scale, int K)
{
    __shared__ ushort As[4 * 8192];   // 64 KB
    __shared__ ushort Bs[4 * 8192];   // 64 KB

    int bx = blockIdx.x;
    int yz = blockIdx.y + gridDim.y * blockIdx.z;
    xcd_swizzle(gridDim.x, gridDim.y * gridDim.z, bx, yz);
    const int by = yz % gridDim.y;
    const int bz = yz / gridDim.y;
    const int tileM = by * 256, tileN = bx * 256;

    floatx4 acc[8][4];
#pragma unroll
    for (int i = 0; i < 8; i++)
#pragma unroll
        for (int j = 0; j < 4; j++) acc[i][j] = (floatx4){0.f, 0.f, 0.f, 0.f};

    gemm_core256(A + (size_t)bz * batchA + (size_t)tileM * lda, lda,
                 B + (size_t)bz * batchB + (size_t)tileN * ldb, ldb,
                 K, As, Bs, acc);

    const size_t coff = TRANS ? ((size_t)tileN * ldc + tileM) : ((size_t)tileM * ldc + tileN);
    void* Cb = (OM == 0) ? (void*)((float*)C + (size_t)bz * batchC + coff)
                         : (void*)((ushort*)C + (size_t)bz * batchC + coff);
    epilogue256<OM, TRANS, HB>(acc, Cb, ldc, HB ? bias + tileN : nullptr, scale);
}

// Fused Q/K/V projections on the pipelined 256^2 core. logical grid (4, 96):
//  y in [0,32): qp = q @ Wq^T + bq
//  y in [32,64): kp = k @ Wk^T + bk
//  y in [64,96): vpt_b = (v_b @ Wv^T + bv)^T   (b = (y-64)/8)
__global__ __launch_bounds__(512, 2)
void qkv_proj256(const ushort* __restrict__ q, const ushort* __restrict__ k,
                 const ushort* __restrict__ v,
                 const ushort* __restrict__ Wq, const ushort* __restrict__ Wk,
                 const ushort* __restrict__ Wv,
                 const float* __restrict__ bq, const float* __restrict__ bk,
                 const float* __restrict__ bv,
                 ushort* __restrict__ qp, ushort* __restrict__ kp,
                 ushort* __restrict__ vpt)
{
    __shared__ ushort As[4 * 8192];
    __shared__ ushort Bs[4 * 8192];
    const int D = 1024, S = 2048;

    int bx = blockIdx.x, y = blockIdx.y;
    xcd_swizzle(4, 96, bx, y);
    const int tileN = bx * 256;

    floatx4 acc[8][4];
#pragma unroll
    for (int i = 0; i < 8; i++)
#pragma unroll
        for (int j = 0; j < 4; j++) acc[i][j] = (floatx4){0.f, 0.f, 0.f, 0.f};

    if (y < 64) {            // block-uniform branch
        const bool isQ = (y < 32);
        const int my = isQ ? y : y - 32;
        const ushort* A = (isQ ? q : k) + (size_t)my * 256 * D;
        const ushort* W = (isQ ? Wq : Wk) + (size_t)tileN * D;
        gemm_core256(A, D, W, D, D, As, Bs, acc);
        ushort* Cb = (isQ ? qp : kp) + (size_t)my * 256 * D + tileN;
        epilogue256<1, false, true>(acc, Cb, D, (isQ ? bq : bk) + tileN, 1.0f);
    } else {
        const int yy = y - 64;
        const int bz = yy >> 3, my = yy & 7;
        const ushort* A = v + ((size_t)bz * S + (size_t)my * 256) * D;
        gemm_core256(A, D, Wv + (size_t)tileN * D, D, D, As, Bs, acc);
        ushort* Cb = vpt + (size_t)bz * D * S + (size_t)tileN * S + (size_t)my * 256;
        epilogue256<1, true, true>(acc, Cb, S, bv + tileN, 1.0f);
    }
}

// fp32 -> fp16 for the 4 weight matrices (D*D each); grid (512, 4)
__global__ __launch_bounds__(256)
void cvt_w(const float* __restrict__ w0, const float* __restrict__ w1,
           const float* __restrict__ w2, const float* __restrict__ w3,
           ushort* __restrict__ o0, ushort* __restrict__ o1,
           ushort* __restrict__ o2, ushort* __restrict__ o3)
{
    const float* src; ushort* dst;
    switch (blockIdx.y) {
        case 0: src = w0; dst = o0; break;
        case 1: src = w1; dst = o1; break;
        case 2: src = w2; dst = o2; break;
        default: src = w3; dst = o3; break;
    }
    const size_t i = ((size_t)blockIdx.x * 256 + threadIdx.x) * 8;
    floatx4 f0 = *(const floatx4*)(src + i);
    floatx4 f1 = *(const floatx4*)(src + i + 4);
    ushortx8 u;
    u[0] = f2h(f0.x); u[1] = f2h(f0.y); u[2] = f2h(f0.z); u[3] = f2h(f0.w);
    u[4] = f2h(f1.x); u[5] = f2h(f1.y); u[6] = f2h(f1.z); u[7] = f2h(f1.w);
    *(ushortx8*)(dst + i) = u;
}

// fp32 -> fp16 for q,k,v activations (B*S*D each); grid (4096, 3).
__global__ __launch_bounds__(256)
void cvt_qkv(const float* __restrict__ q, const float* __restrict__ k,
             const float* __restrict__ v,
             ushort* __restrict__ qh, ushort* __restrict__ kh,
             ushort* __restrict__ vh)
{
    const float* src; ushort* dst;
    switch (blockIdx.y) {
        case 0: src = q; dst = qh; break;
        case 1: src = k; dst = kh; break;
        default: src = v; dst = vh; break;
    }
    const size_t i = ((size_t)blockIdx.x * 256 + threadIdx.x) * 8;
    floatx4 f0 = *(const floatx4*)(src + i);
    floatx4 f1 = *(const floatx4*)(src + i + 4);
    ushortx8 u;
    u[0] = f2h(f0.x); u[1] = f2h(f0.y); u[2] = f2h(f0.z); u[3] = f2h(f0.w);
    u[4] = f2h(f1.x); u[5] = f2h(f1.y); u[6] = f2h(f1.z); u[7] = f2h(f1.w);
    *(ushortx8*)(dst + i) = u;
}

// Row softmax over S=2048 pre-scaled fp16 logits; fp32 math; fp16 probs in place.
__global__ __launch_bounds__(256)
void softmax_rows(ushort* __restrict__ scores)
{
    const int S = 2048;
    ushort* srow = scores + (size_t)blockIdx.x * S;
    const int t    = threadIdx.x;
    const int lane = t & 63;
    const int w    = t >> 6;

    ushortx8 raw = *(const ushortx8*)(srow + t * 8);
    float l[8];
#pragma unroll
    for (int i = 0; i < 8; i++) l[i] = h2f(raw[i]);

    float m = l[0];
#pragma unroll
    for (int i = 1; i < 8; i++) m = fmaxf(m, l[i]);
#pragma unroll
    for (int off = 32; off >= 1; off >>= 1) m = fmaxf(m, __shfl_down(m, off));

    __shared__ float redm[4], reds[4];
    if (lane == 0) redm[w] = m;
    __syncthreads();
    m = fmaxf(fmaxf(redm[0], redm[1]), fmaxf(redm[2], redm[3]));

    float e[8], s = 0.f;
#pragma unroll
    for (int i = 0; i < 8; i++) { e[i] = __expf(l[i] - m); s += e[i]; }
#pragma unroll
    for (int off = 32; off >= 1; off >>= 1) s += __shfl_down(s, off);
    if (lane == 0) reds[w] = s;
    __syncthreads();
    s = reds[0] + reds[1] + reds[2] + reds[3];
    const float inv = 1.f / s;

    ushortx8 o;
#pragma unroll
    for (int i = 0; i < 8; i++) o[i] = f2h(e[i] * inv);
    *(ushortx8*)(srow + t * 8) = o;
}

extern "C" void kernel_launch(void* const* d_in, const int* in_sizes, int n_in,
                              void* d_out, int out_size, void* d_ws, size_t ws_size,
                              hipStream_t stream)
{
    const int B = 4, S = 2048, D = 1024;
    const size_t SD = (size_t)B * S * D;   // 8M elems
    const float* q  = (const float*)d_in[0];
    const float* k  = (const float*)d_in[1];
    const float* v  = (const float*)d_in[2];
    const float* Wq = (const float*)d_in[3];
    const float* bq = (const float*)d_in[4];
    const float* Wk = (const float*)d_in[5];
    const float* bk = (const float*)d_in[6];
    const float* Wv = (const float*)d_in[7];
    const float* bv = (const float*)d_in[8];
    const float* Wo = (const float*)d_in[9];
    const float* bo = (const float*)d_in[10];
    float* out = (float*)d_out;

    // ws (ushort): qp 16MB | kp 16MB | sc 33.5MB | W16 x4 8MB | vpt 16MB | attn 16MB
    ushort* qp   = (ushort*)d_ws;
    ushort* kp   = qp + SD;
    ushort* sc   = kp + SD;                        // [B][S][S]
    ushort* Wq16 = sc + (size_t)B * S * S;
    ushort* Wk16 = Wq16 + (size_t)D * D;
    ushort* Wv16 = Wk16 + (size_t)D * D;
    ushort* Wo16 = Wv16 + (size_t)D * D;
    ushort* vpt  = Wo16 + (size_t)D * D;           // per batch [D][S]
    ushort* attn = vpt + SD;                       // [B*S][D]

    // fp16 staging of q,k,v: dead after qkv_proj, so alias late-written regions.
    ushort* qh = sc;                               // 16MB of sc's 33.5MB
    ushort* kh = sc + SD;                          // next 16MB of sc
    ushort* vh = attn;                             // 16MB

    dim3 blk(256);
    dim3 blk512(512);

    cvt_w<<<dim3(D * D / 2048, 4), blk, 0, stream>>>(Wq, Wk, Wv, Wo, Wq16, Wk16, Wv16, Wo16);
    cvt_qkv<<<dim3(SD / 2048, 3), blk, 0, stream>>>(q, k, v, qh, kh, vh);

    // qp/kp/vpt in one dispatch, pipelined 256^2 core
    qkv_proj256<<<dim3(D / 256, 96), blk512, 0, stream>>>(
        qh, kh, vh, Wq16, Wk16, Wv16, bq, bk, bv, qp, kp, vpt);

    // sc = 0.125 * qp @ kp^T  (pre-scaled fp16 logits), pipelined 256^2 core
    gemm_nt256<1, false, false><<<dim3(S / 256, S / 256, B), blk512, 0, stream>>>(
        qp, (long long)S * D, D, kp, (long long)S * D, D,
        sc, (long long)S * S, S, nullptr, 0.125f, D);

    softmax_rows<<<dim3(B * S), blk, 0, stream>>>(sc);

    // attn = probs @ vp  (vp given as vpt rows) — 128^2 core (grid too small for 256^2)
    gemm_nt<1, false, false><<<dim3(D / TILE, S / TILE, B), blk, 0, stream>>>(
        sc, (long long)S * S, S, vpt, (long long)D * S, S,
        attn, (long long)S * D, D, nullptr, 1.0f, S);

    // out = attn @ Wo^T + bo  (fp32 out) — 128^2 core
    gemm_nt<0, false, true><<<dim3(D / TILE, (B * S) / TILE, 1), blk, 0, stream>>>(
        attn, 0, D, Wo16, 0, D, out, 0, D, bo, 1.0f, D);
}